// Round 7
// baseline (348.142 us; speedup 1.0000x reference)
//
#include <hip/hip_runtime.h>

// ---------------- Problem constants ----------------
#define BATCH 16
#define TSEQ  4096
#define HDIM  512
#define NDIM  512
#define NCHUNK 64
#define LCHUNK 64   // TSEQ / NCHUNK

using f32x4  = __attribute__((ext_vector_type(4))) float;
using bf16x8 = __attribute__((ext_vector_type(8))) short;

typedef const __attribute__((address_space(1))) void GV;
typedef __attribute__((address_space(3))) void LV;

__device__ __forceinline__ void gload16(const void* g, void* l) {
  __builtin_amdgcn_global_load_lds((GV*)g, (LV*)l, 16, 0, 0);
}
__device__ __forceinline__ unsigned short f2bf(float f) {
  unsigned u = __float_as_uint(f);
  return (unsigned short)((u + 0x7fffu + ((u >> 16) & 1u)) >> 16);
}
__device__ __forceinline__ float bf2f(unsigned short s) {
  return __uint_as_float(((unsigned)s) << 16);
}

// ---------------- Param prep ----------------
__global__ void prep_params(const float* __restrict__ nu_log,
                            const float* __restrict__ theta_log,
                            float* lam_re, float* lam_im, float* gam,
                            float* lamL_re, float* lamL_im) {
  int n = threadIdx.x;
  float en = expf(nu_log[n]);
  float th = expf(theta_log[n]);
  float r  = expf(-en);
  lam_re[n] = r * cosf(th);
  lam_im[n] = r * sinf(th);
  float r2 = expf(-2.f * en);
  gam[n] = sqrtf(fmaxf(1.f - r2, 0.f));
  float rL  = expf(-(float)LCHUNK * en);
  float thL = (float)LCHUNK * th;
  lamL_re[n] = rL * cosf(thL);
  lamL_im[n] = rL * sinf(thL);
}

__global__ void prep_bcat(const float* __restrict__ B_re, const float* __restrict__ B_im,
                          const float* __restrict__ gam, unsigned short* __restrict__ Bcat) {
  int idx = blockIdx.x * 256 + threadIdx.x;
  int h   = idx & (HDIM - 1);
  int row = idx >> 9;
  int n   = row >> 1;
  float g = gam[n];
  float v = (row & 1) ? B_im[n * HDIM + h] : B_re[n * HDIM + h];
  Bcat[idx] = f2bf(g * v);
}

__global__ void prep_ccat(const float* __restrict__ C_re, const float* __restrict__ C_im,
                          unsigned short* __restrict__ Ccat) {
  int idx = blockIdx.x * 256 + threadIdx.x;
  int col = idx & (2 * NDIM - 1);
  int h   = idx >> 10;
  int n   = col >> 1;
  float v = (col & 1) ? -C_im[h * NDIM + n] : C_re[h * NDIM + n];
  Ccat[idx] = f2bf(v);
}

__global__ void conv_u(const float4* __restrict__ u, ushort4* __restrict__ ub, int n4) {
  int idx = blockIdx.x * 256 + threadIdx.x;
  if (idx >= n4) return;
  float4 v = u[idx];
  ushort4 o;
  o.x = f2bf(v.x); o.y = f2bf(v.y); o.z = f2bf(v.z); o.w = f2bf(v.w);
  ub[idx] = o;
}

// ---------------- 128x128 bf16 MFMA GEMM (m97 structure + T2 swizzle + T1) ----
// C[M,Nd] = A[M,K] @ Bm[Nd,K]^T.  OUTBF: write bf16 (GEMM1->Bu),
// else f32 out + D*u epilogue (GEMM2->outs).
// Proven m97 shape: 256 threads (4 waves, 2x2 of 64x64), BK=64, SINGLE 32KiB
// LDS buffer, plain __syncthreads() pairs (full drain = the proven 874-912 TF
// structure). Added over round 2:
//  - T2 XOR-swizzle byte ^= ((row&7)<<4): staging uses pre-swizzled global
//    source (linear LDS dest), ds_read applies the same XOR -> 2-way max
//    aliasing (free, m136) instead of 2.5e7 conflicts.
//  - T1 XCD chunking, col-block fastest inside each XCD's contiguous chunk:
//    one A row-panel is reused by all col-blocks within the same XCD's L2.
template <int K, bool OUTBF>
__global__ __launch_bounds__(256)
void gemm97(const unsigned short* __restrict__ A,
            const unsigned short* __restrict__ Bm,
            void* __restrict__ Co, int Ncol, int Nd,
            const unsigned short* __restrict__ ub,
            const float* __restrict__ Dv) {
  __shared__ char lds[65536];  // [A: 0..32767][B: 32768..65535], 128 rows x 128 B
  const int tid  = threadIdx.x;
  const int wave = tid >> 6, lane = tid & 63;
  const int wr = (wave >> 1) * 64, wc = (wave & 1) * 64;

  // T1: XCD chunking (nwg % 8 == 0), col-block fastest within a chunk.
  int nwg = gridDim.x;
  int bid = blockIdx.x;
  int wg  = (bid & 7) * (nwg >> 3) + (bid >> 3);
  int bn = wg % Ncol, bm = wg / Ncol;
  const long rowBase = (long)bm * 128;
  const long colBase = (long)bn * 128;

  // Pre-swizzled global sources. Linear LDS byte X holds global
  // (row = X>>7, colbyte = (X&127) ^ ((row&7)<<4)).  Per-thread dst
  // X = r*4096 + tid*16  ->  row = r*32 + (tid>>3), colE = 8*((tid&7)^((tid>>3)&7))
  const int colE = 8 * ((tid & 7) ^ ((tid >> 3) & 7));
  const unsigned short* srcA[4];
  const unsigned short* srcB[4];
#pragma unroll
  for (int r = 0; r < 4; r++) {
    srcA[r] = A  + (rowBase + r * 32 + (tid >> 3)) * (long)K + colE;
    srcB[r] = Bm + (colBase + r * 32 + (tid >> 3)) * (long)K + colE;
  }

  f32x4 acc[4][4];
#pragma unroll
  for (int i = 0; i < 4; i++)
#pragma unroll
    for (int j = 0; j < 4; j++) acc[i][j] = (f32x4){0.f, 0.f, 0.f, 0.f};

  const int rsub = lane & 15;
  const int sx   = (lane & 7) << 4;      // row&7 == lane&7 for all fragment rows
  const int ke   = (lane >> 4) << 4;     // k-subgroup byte offset (8 elems)

  for (int kt = 0; kt < K; kt += 64) {
    __syncthreads();  // previous tile's readers done before overwrite
#pragma unroll
    for (int r = 0; r < 4; r++) {
      gload16(srcA[r] + kt, &lds[r * 4096 + tid * 16]);
      gload16(srcB[r] + kt, &lds[32768 + r * 4096 + tid * 16]);
    }
    __syncthreads();  // full drain (vmcnt0) + barrier: tile visible to all
#pragma unroll
    for (int kk = 0; kk < 64; kk += 32) {
      bf16x8 af[4], bf[4];
#pragma unroll
      for (int i = 0; i < 4; i++) {
        int off = (((wr + i * 16 + rsub) << 7) + kk * 2 + ke) ^ sx;
        af[i] = *(const bf16x8*)&lds[off];
      }
#pragma unroll
      for (int j = 0; j < 4; j++) {
        int off = 32768 + ((((wc + j * 16 + rsub) << 7) + kk * 2 + ke) ^ sx);
        bf[j] = *(const bf16x8*)&lds[off];
      }
#pragma unroll
      for (int i = 0; i < 4; i++)
#pragma unroll
        for (int j = 0; j < 4; j++)
          acc[i][j] = __builtin_amdgcn_mfma_f32_16x16x32_bf16(af[i], bf[j], acc[i][j], 0, 0, 0);
    }
  }

  // Epilogue (proven round-2 mapping: col=lane&15, row=(lane>>4)*4+r)
  const int cc = lane & 15, r4 = (lane >> 4) * 4;
#pragma unroll
  for (int i = 0; i < 4; i++) {
#pragma unroll
    for (int j = 0; j < 4; j++) {
      long col = colBase + wc + j * 16 + cc;
#pragma unroll
      for (int r = 0; r < 4; r++) {
        long row = rowBase + wr + i * 16 + r4 + r;
        if (OUTBF) {
          ((unsigned short*)Co)[row * (long)Nd + col] = f2bf(acc[i][j][r]);
        } else {
          float d = Dv[col];
          ((float*)Co)[row * (long)Nd + col] =
              acc[i][j][r] + d * bf2f(ub[row * (long)Nd + col]);
        }
      }
    }
  }
}

// ---------------- Chunked complex scan (Bu packed bf16 re|im) ----------------
__global__ void scan_carry(const unsigned* __restrict__ Bu,
                           const float* __restrict__ lam_re, const float* __restrict__ lam_im,
                           float2* __restrict__ V) {
  int idx  = blockIdx.x * 256 + threadIdx.x;
  int n    = idx & (NDIM - 1);
  int c    = (idx >> 9) & (NCHUNK - 1);
  int bloc = idx >> 15;
  float lr = lam_re[n], li = lam_im[n];
  float xr = 0.f, xi = 0.f;
  long base = ((long)bloc * TSEQ + c * LCHUNK) * NDIM + n;
#pragma unroll 4
  for (int j = 0; j < LCHUNK; j++) {
    unsigned pv = Bu[base + (long)j * NDIM];
    float br = bf2f((unsigned short)(pv & 0xffff));
    float bi = bf2f((unsigned short)(pv >> 16));
    float nr = lr * xr - li * xi + br;
    float ni = lr * xi + li * xr + bi;
    xr = nr; xi = ni;
  }
  V[idx] = make_float2(xr, xi);
}

__global__ void scan_combine(const float2* __restrict__ V,
                             const float* __restrict__ lamL_re, const float* __restrict__ lamL_im,
                             const float* __restrict__ x0r, const float* __restrict__ x0i,
                             int b0, float2* __restrict__ In) {
  int idx  = blockIdx.x * 256 + threadIdx.x;
  int n    = idx & (NDIM - 1);
  int bloc = idx >> 9;
  int b    = b0 + bloc;
  float lr = lamL_re[n], li = lamL_im[n];
  float sr = x0r[b * NDIM + n], si = x0i[b * NDIM + n];
  long base = (long)bloc * NCHUNK * NDIM + n;
  for (int c = 0; c < NCHUNK; c++) {
    In[base + c * NDIM] = make_float2(sr, si);
    float2 v = V[base + c * NDIM];
    float nr = lr * sr - li * si + v.x;
    float ni = lr * si + li * sr + v.y;
    sr = nr; si = ni;
  }
}

__global__ void scan_apply(const unsigned* __restrict__ Bu, const float2* __restrict__ In,
                           const float* __restrict__ lam_re, const float* __restrict__ lam_im,
                           unsigned int* __restrict__ xsb, float* __restrict__ fs,
                           int b0, int fs_mode) {
  int idx  = blockIdx.x * 256 + threadIdx.x;
  int n    = idx & (NDIM - 1);
  int c    = (idx >> 9) & (NCHUNK - 1);
  int bloc = idx >> 15;
  float lr = lam_re[n], li = lam_im[n];
  float2 s = In[idx];
  float xr = s.x, xi = s.y;
  long base = ((long)bloc * TSEQ + c * LCHUNK) * NDIM + n;
#pragma unroll 4
  for (int j = 0; j < LCHUNK; j++) {
    unsigned pv = Bu[base + (long)j * NDIM];
    float br = bf2f((unsigned short)(pv & 0xffff));
    float bi = bf2f((unsigned short)(pv >> 16));
    float nr = lr * xr - li * xi + br;
    float ni = lr * xi + li * xr + bi;
    xr = nr; xi = ni;
    xsb[base + (long)j * NDIM] = (unsigned)f2bf(xr) | ((unsigned)f2bf(xi) << 16);
  }
  if (c == NCHUNK - 1 && fs_mode >= 0) {
    int b = b0 + bloc;
    if (fs_mode == 1) {
      fs[(size_t)(b * NDIM + n) * 2]     = xr;
      fs[(size_t)(b * NDIM + n) * 2 + 1] = xi;
    } else {
      fs[(size_t)(b * NDIM + n)] = xr;
    }
  }
}

// ---------------- Host launch ----------------
extern "C" void kernel_launch(void* const* d_in, const int* in_sizes, int n_in,
                              void* d_out, int out_size, void* d_ws, size_t ws_size,
                              hipStream_t stream) {
  const float* x0r       = (const float*)d_in[0];
  const float* x0i       = (const float*)d_in[1];
  const float* u         = (const float*)d_in[2];
  const float* nu_log    = (const float*)d_in[3];
  const float* theta_log = (const float*)d_in[4];
  const float* B_re      = (const float*)d_in[5];
  const float* B_im      = (const float*)d_in[6];
  const float* C_re      = (const float*)d_in[7];
  const float* C_im      = (const float*)d_in[8];
  const float* Dv        = (const float*)d_in[9];

  char* ws = (char*)d_ws;
  size_t off = 0;
  auto alloc = [&](size_t bytes) {
    char* p = ws + off;
    off = (off + bytes + 255) & ~(size_t)255;
    return p;
  };

  float* lam_re  = (float*)alloc(NDIM * 4);
  float* lam_im  = (float*)alloc(NDIM * 4);
  float* gam     = (float*)alloc(NDIM * 4);
  float* lamL_re = (float*)alloc(NDIM * 4);
  float* lamL_im = (float*)alloc(NDIM * 4);
  unsigned short* Bcat = (unsigned short*)alloc((size_t)2 * NDIM * HDIM * 2);
  unsigned short* Ccat = (unsigned short*)alloc((size_t)HDIM * 2 * NDIM * 2);

  const size_t per_batch =
      (size_t)TSEQ * HDIM * 2 +       // u bf16
      (size_t)TSEQ * NDIM * 4 +       // Bu packed bf16 (re|im)
      (size_t)TSEQ * NDIM * 4 +       // xs packed bf16
      (size_t)2 * NCHUNK * NDIM * 8 + // V, In
      4096;
  int G = 16;
  while (G > 1 && off + (size_t)G * per_batch > ws_size) G >>= 1;

  ushort4*      ub  = (ushort4*)alloc((size_t)G * TSEQ * HDIM * 2);
  unsigned*     Bu  = (unsigned*)alloc((size_t)G * TSEQ * NDIM * 4);
  unsigned int* xsb = (unsigned int*)alloc((size_t)G * TSEQ * NDIM * 4);
  float2*       V   = (float2*)alloc((size_t)G * NCHUNK * NDIM * 8);
  float2*       In  = (float2*)alloc((size_t)G * NCHUNK * NDIM * 8);

  const long outs_elems = (long)BATCH * TSEQ * HDIM;
  long out0 = (long)out_size - outs_elems;
  int fs_mode;
  if (out0 >= 16384)     fs_mode = 1;
  else if (out0 >= 8192) fs_mode = 0;
  else { out0 = 0;       fs_mode = -1; }

  float* fs   = (float*)d_out;
  float* outs = (float*)d_out + out0;

  prep_params<<<1, NDIM, 0, stream>>>(nu_log, theta_log, lam_re, lam_im, gam, lamL_re, lamL_im);
  prep_bcat<<<(2 * NDIM * HDIM) / 256, 256, 0, stream>>>(B_re, B_im, gam, Bcat);
  prep_ccat<<<(HDIM * 2 * NDIM) / 256, 256, 0, stream>>>(C_re, C_im, Ccat);

  for (int b0 = 0; b0 < BATCH; b0 += G) {
    const float* ug = u + (size_t)b0 * TSEQ * HDIM;
    int Mloc = G * TSEQ;
    int n4 = Mloc * HDIM / 4;
    conv_u<<<(n4 + 255) / 256, 256, 0, stream>>>((const float4*)ug, ub, n4);

    // GEMM1: Bu[M, 2N] (bf16 packed) = ub[M,512] @ Bcat[1024,512]^T
    int nwg1 = (Mloc / 128) * 8;
    gemm97<512, true><<<nwg1, 256, 0, stream>>>(
        (const unsigned short*)ub, Bcat, Bu, 8, 2 * NDIM, nullptr, nullptr);

    scan_carry<<<(G * NCHUNK * NDIM) / 256, 256, 0, stream>>>(Bu, lam_re, lam_im, V);
    scan_combine<<<(G * NDIM) / 256, 256, 0, stream>>>(
        V, lamL_re, lamL_im, x0r, x0i, b0, In);
    scan_apply<<<(G * NCHUNK * NDIM) / 256, 256, 0, stream>>>(
        Bu, In, lam_re, lam_im, xsb, fs, b0, fs_mode);

    // GEMM2: outs[M,512] = xsb[M,1024] @ Ccat[512,1024]^T + D*u
    int nwg2 = (Mloc / 128) * 4;
    gemm97<1024, false><<<nwg2, 256, 0, stream>>>(
        (const unsigned short*)xsb, Ccat, outs + (size_t)b0 * TSEQ * HDIM,
        4, HDIM, (const unsigned short*)ub, Dv);
  }
}

// Round 8
// 346.506 us; speedup vs baseline: 1.0047x; 1.0047x over previous
//
#include <hip/hip_runtime.h>

// ---------------- Problem constants ----------------
#define BATCH 16
#define TSEQ  4096
#define HDIM  512
#define NDIM  512
#define NCHUNK 64
#define LCHUNK 64   // TSEQ / NCHUNK

using f32x4  = __attribute__((ext_vector_type(4))) float;
using bf16x8 = __attribute__((ext_vector_type(8))) short;

typedef const __attribute__((address_space(1))) void GV;
typedef __attribute__((address_space(3))) void LV;

__device__ __forceinline__ void gload16(const void* g, void* l) {
  __builtin_amdgcn_global_load_lds((GV*)g, (LV*)l, 16, 0, 0);
}
__device__ __forceinline__ unsigned short f2bf(float f) {
  unsigned u = __float_as_uint(f);
  return (unsigned short)((u + 0x7fffu + ((u >> 16) & 1u)) >> 16);
}
__device__ __forceinline__ float bf2f(unsigned short s) {
  return __uint_as_float(((unsigned)s) << 16);
}

// ---------------- Param prep ----------------
__global__ void prep_params(const float* __restrict__ nu_log,
                            const float* __restrict__ theta_log,
                            float* lam_re, float* lam_im, float* gam,
                            float* lamL_re, float* lamL_im) {
  int n = threadIdx.x;
  float en = expf(nu_log[n]);
  float th = expf(theta_log[n]);
  float r  = expf(-en);
  lam_re[n] = r * cosf(th);
  lam_im[n] = r * sinf(th);
  float r2 = expf(-2.f * en);
  gam[n] = sqrtf(fmaxf(1.f - r2, 0.f));
  float rL  = expf(-(float)LCHUNK * en);
  float thL = (float)LCHUNK * th;
  lamL_re[n] = rL * cosf(thL);
  lamL_im[n] = rL * sinf(thL);
}

__global__ void prep_bcat(const float* __restrict__ B_re, const float* __restrict__ B_im,
                          const float* __restrict__ gam, unsigned short* __restrict__ Bcat) {
  int idx = blockIdx.x * 256 + threadIdx.x;
  int h   = idx & (HDIM - 1);
  int row = idx >> 9;
  int n   = row >> 1;
  float g = gam[n];
  float v = (row & 1) ? B_im[n * HDIM + h] : B_re[n * HDIM + h];
  Bcat[idx] = f2bf(g * v);
}

__global__ void prep_ccat(const float* __restrict__ C_re, const float* __restrict__ C_im,
                          unsigned short* __restrict__ Ccat) {
  int idx = blockIdx.x * 256 + threadIdx.x;
  int col = idx & (2 * NDIM - 1);
  int h   = idx >> 10;
  int n   = col >> 1;
  float v = (col & 1) ? -C_im[h * NDIM + n] : C_re[h * NDIM + n];
  Ccat[idx] = f2bf(v);
}

__global__ void conv_u(const float4* __restrict__ u, ushort4* __restrict__ ub, int n4) {
  int idx = blockIdx.x * 256 + threadIdx.x;
  if (idx >= n4) return;
  float4 v = u[idx];
  ushort4 o;
  o.x = f2bf(v.x); o.y = f2bf(v.y); o.z = f2bf(v.z); o.w = f2bf(v.w);
  ub[idx] = o;
}

// ---------------- 128x128 bf16 MFMA GEMM (m97 structure + T2 swizzle + T1) ----
// C[M,Nd] = A[M,K] @ Bm[Nd,K]^T.  OUTBF: write bf16 (GEMM1->Bu),
// else f32 out + D*u epilogue (GEMM2->outs).
// m97 shape: 256 threads (4 waves, 2x2 of 64x64), BK=64, SINGLE LDS buffer,
// plain __syncthreads() pairs. LDS = 32 KiB TOTAL (A 0..16383, B 16384..32767;
// round 7 wasted 2x -> 2 blocks/CU; this restores 4 blocks/CU occupancy).
//  - T2 XOR-swizzle byte ^= ((row&7)<<4), staged via pre-swizzled global src.
//  - T1 XCD chunking, col-block fastest inside each XCD's contiguous chunk.
template <int K, bool OUTBF>
__global__ __launch_bounds__(256)
void gemm97(const unsigned short* __restrict__ A,
            const unsigned short* __restrict__ Bm,
            void* __restrict__ Co, int Ncol, int Nd,
            const unsigned short* __restrict__ ub,
            const float* __restrict__ Dv) {
  __shared__ char lds[32768];  // [A: 0..16383][B: 16384..32767], 128 rows x 128 B each
  const int tid  = threadIdx.x;
  const int wave = tid >> 6, lane = tid & 63;
  const int wr = (wave >> 1) * 64, wc = (wave & 1) * 64;

  // T1: XCD chunking (nwg % 8 == 0), col-block fastest within a chunk.
  int nwg = gridDim.x;
  int bid = blockIdx.x;
  int wg  = (bid & 7) * (nwg >> 3) + (bid >> 3);
  int bn = wg % Ncol, bm = wg / Ncol;
  const long rowBase = (long)bm * 128;
  const long colBase = (long)bn * 128;

  // Pre-swizzled global sources. Linear LDS byte X holds global
  // (row = X>>7, colbyte = (X&127) ^ ((row&7)<<4)).  Per-thread dst
  // X = r*4096 + tid*16 -> row = r*32 + (tid>>3), colE = 8*((tid&7)^((tid>>3)&7))
  const int colE = 8 * ((tid & 7) ^ ((tid >> 3) & 7));
  const unsigned short* srcA[4];
  const unsigned short* srcB[4];
#pragma unroll
  for (int r = 0; r < 4; r++) {
    srcA[r] = A  + (rowBase + r * 32 + (tid >> 3)) * (long)K + colE;
    srcB[r] = Bm + (colBase + r * 32 + (tid >> 3)) * (long)K + colE;
  }

  f32x4 acc[4][4];
#pragma unroll
  for (int i = 0; i < 4; i++)
#pragma unroll
    for (int j = 0; j < 4; j++) acc[i][j] = (f32x4){0.f, 0.f, 0.f, 0.f};

  const int rsub = lane & 15;
  const int sx   = (lane & 7) << 4;      // row&7 == lane&7 for all fragment rows
  const int ke   = (lane >> 4) << 4;     // k-subgroup byte offset (8 elems)

  for (int kt = 0; kt < K; kt += 64) {
    __syncthreads();  // previous tile's readers done before overwrite
#pragma unroll
    for (int r = 0; r < 4; r++) {
      gload16(srcA[r] + kt, &lds[r * 4096 + tid * 16]);
      gload16(srcB[r] + kt, &lds[16384 + r * 4096 + tid * 16]);
    }
    __syncthreads();  // full drain (vmcnt0) + barrier: tile visible to all
#pragma unroll
    for (int kk = 0; kk < 64; kk += 32) {
      bf16x8 af[4], bf[4];
#pragma unroll
      for (int i = 0; i < 4; i++) {
        int off = (((wr + i * 16 + rsub) << 7) + kk * 2 + ke) ^ sx;
        af[i] = *(const bf16x8*)&lds[off];
      }
#pragma unroll
      for (int j = 0; j < 4; j++) {
        int off = 16384 + ((((wc + j * 16 + rsub) << 7) + kk * 2 + ke) ^ sx);
        bf[j] = *(const bf16x8*)&lds[off];
      }
#pragma unroll
      for (int i = 0; i < 4; i++)
#pragma unroll
        for (int j = 0; j < 4; j++)
          acc[i][j] = __builtin_amdgcn_mfma_f32_16x16x32_bf16(af[i], bf[j], acc[i][j], 0, 0, 0);
    }
  }

  // Epilogue (proven mapping: col=lane&15, row=(lane>>4)*4+r)
  const int cc = lane & 15, r4 = (lane >> 4) * 4;
#pragma unroll
  for (int i = 0; i < 4; i++) {
#pragma unroll
    for (int j = 0; j < 4; j++) {
      long col = colBase + wc + j * 16 + cc;
#pragma unroll
      for (int r = 0; r < 4; r++) {
        long row = rowBase + wr + i * 16 + r4 + r;
        if (OUTBF) {
          ((unsigned short*)Co)[row * (long)Nd + col] = f2bf(acc[i][j][r]);
        } else {
          float d = Dv[col];
          ((float*)Co)[row * (long)Nd + col] =
              acc[i][j][r] + d * bf2f(ub[row * (long)Nd + col]);
        }
      }
    }
  }
}

// ---------------- Chunked complex scan (Bu packed bf16 re|im) ----------------
__global__ void scan_carry(const unsigned* __restrict__ Bu,
                           const float* __restrict__ lam_re, const float* __restrict__ lam_im,
                           float2* __restrict__ V) {
  int idx  = blockIdx.x * 256 + threadIdx.x;
  int n    = idx & (NDIM - 1);
  int c    = (idx >> 9) & (NCHUNK - 1);
  int bloc = idx >> 15;
  float lr = lam_re[n], li = lam_im[n];
  float xr = 0.f, xi = 0.f;
  long base = ((long)bloc * TSEQ + c * LCHUNK) * NDIM + n;
#pragma unroll 4
  for (int j = 0; j < LCHUNK; j++) {
    unsigned pv = Bu[base + (long)j * NDIM];
    float br = bf2f((unsigned short)(pv & 0xffff));
    float bi = bf2f((unsigned short)(pv >> 16));
    float nr = lr * xr - li * xi + br;
    float ni = lr * xi + li * xr + bi;
    xr = nr; xi = ni;
  }
  V[idx] = make_float2(xr, xi);
}

__global__ void scan_combine(const float2* __restrict__ V,
                             const float* __restrict__ lamL_re, const float* __restrict__ lamL_im,
                             const float* __restrict__ x0r, const float* __restrict__ x0i,
                             int b0, float2* __restrict__ In) {
  int idx  = blockIdx.x * 256 + threadIdx.x;
  int n    = idx & (NDIM - 1);
  int bloc = idx >> 9;
  int b    = b0 + bloc;
  float lr = lamL_re[n], li = lamL_im[n];
  float sr = x0r[b * NDIM + n], si = x0i[b * NDIM + n];
  long base = (long)bloc * NCHUNK * NDIM + n;
  for (int c = 0; c < NCHUNK; c++) {
    In[base + c * NDIM] = make_float2(sr, si);
    float2 v = V[base + c * NDIM];
    float nr = lr * sr - li * si + v.x;
    float ni = lr * si + li * sr + v.y;
    sr = nr; si = ni;
  }
}

__global__ void scan_apply(const unsigned* __restrict__ Bu, const float2* __restrict__ In,
                           const float* __restrict__ lam_re, const float* __restrict__ lam_im,
                           unsigned int* __restrict__ xsb, float* __restrict__ fs,
                           int b0, int fs_mode) {
  int idx  = blockIdx.x * 256 + threadIdx.x;
  int n    = idx & (NDIM - 1);
  int c    = (idx >> 9) & (NCHUNK - 1);
  int bloc = idx >> 15;
  float lr = lam_re[n], li = lam_im[n];
  float2 s = In[idx];
  float xr = s.x, xi = s.y;
  long base = ((long)bloc * TSEQ + c * LCHUNK) * NDIM + n;
#pragma unroll 4
  for (int j = 0; j < LCHUNK; j++) {
    unsigned pv = Bu[base + (long)j * NDIM];
    float br = bf2f((unsigned short)(pv & 0xffff));
    float bi = bf2f((unsigned short)(pv >> 16));
    float nr = lr * xr - li * xi + br;
    float ni = lr * xi + li * xr + bi;
    xr = nr; xi = ni;
    xsb[base + (long)j * NDIM] = (unsigned)f2bf(xr) | ((unsigned)f2bf(xi) << 16);
  }
  if (c == NCHUNK - 1 && fs_mode >= 0) {
    int b = b0 + bloc;
    if (fs_mode == 1) {
      fs[(size_t)(b * NDIM + n) * 2]     = xr;
      fs[(size_t)(b * NDIM + n) * 2 + 1] = xi;
    } else {
      fs[(size_t)(b * NDIM + n)] = xr;
    }
  }
}

// ---------------- Host launch ----------------
extern "C" void kernel_launch(void* const* d_in, const int* in_sizes, int n_in,
                              void* d_out, int out_size, void* d_ws, size_t ws_size,
                              hipStream_t stream) {
  const float* x0r       = (const float*)d_in[0];
  const float* x0i       = (const float*)d_in[1];
  const float* u         = (const float*)d_in[2];
  const float* nu_log    = (const float*)d_in[3];
  const float* theta_log = (const float*)d_in[4];
  const float* B_re      = (const float*)d_in[5];
  const float* B_im      = (const float*)d_in[6];
  const float* C_re      = (const float*)d_in[7];
  const float* C_im      = (const float*)d_in[8];
  const float* Dv        = (const float*)d_in[9];

  char* ws = (char*)d_ws;
  size_t off = 0;
  auto alloc = [&](size_t bytes) {
    char* p = ws + off;
    off = (off + bytes + 255) & ~(size_t)255;
    return p;
  };

  float* lam_re  = (float*)alloc(NDIM * 4);
  float* lam_im  = (float*)alloc(NDIM * 4);
  float* gam     = (float*)alloc(NDIM * 4);
  float* lamL_re = (float*)alloc(NDIM * 4);
  float* lamL_im = (float*)alloc(NDIM * 4);
  unsigned short* Bcat = (unsigned short*)alloc((size_t)2 * NDIM * HDIM * 2);
  unsigned short* Ccat = (unsigned short*)alloc((size_t)HDIM * 2 * NDIM * 2);

  const size_t per_batch =
      (size_t)TSEQ * HDIM * 2 +       // u bf16
      (size_t)TSEQ * NDIM * 4 +       // Bu packed bf16 (re|im)
      (size_t)TSEQ * NDIM * 4 +       // xs packed bf16
      (size_t)2 * NCHUNK * NDIM * 8 + // V, In
      4096;
  int G = 16;
  while (G > 1 && off + (size_t)G * per_batch > ws_size) G >>= 1;

  ushort4*      ub  = (ushort4*)alloc((size_t)G * TSEQ * HDIM * 2);
  unsigned*     Bu  = (unsigned*)alloc((size_t)G * TSEQ * NDIM * 4);
  unsigned int* xsb = (unsigned int*)alloc((size_t)G * TSEQ * NDIM * 4);
  float2*       V   = (float2*)alloc((size_t)G * NCHUNK * NDIM * 8);
  float2*       In  = (float2*)alloc((size_t)G * NCHUNK * NDIM * 8);

  const long outs_elems = (long)BATCH * TSEQ * HDIM;
  long out0 = (long)out_size - outs_elems;
  int fs_mode;
  if (out0 >= 16384)     fs_mode = 1;
  else if (out0 >= 8192) fs_mode = 0;
  else { out0 = 0;       fs_mode = -1; }

  float* fs   = (float*)d_out;
  float* outs = (float*)d_out + out0;

  prep_params<<<1, NDIM, 0, stream>>>(nu_log, theta_log, lam_re, lam_im, gam, lamL_re, lamL_im);
  prep_bcat<<<(2 * NDIM * HDIM) / 256, 256, 0, stream>>>(B_re, B_im, gam, Bcat);
  prep_ccat<<<(HDIM * 2 * NDIM) / 256, 256, 0, stream>>>(C_re, C_im, Ccat);

  for (int b0 = 0; b0 < BATCH; b0 += G) {
    const float* ug = u + (size_t)b0 * TSEQ * HDIM;
    int Mloc = G * TSEQ;
    int n4 = Mloc * HDIM / 4;
    conv_u<<<(n4 + 255) / 256, 256, 0, stream>>>((const float4*)ug, ub, n4);

    // GEMM1: Bu[M, 2N] (bf16 packed) = ub[M,512] @ Bcat[1024,512]^T
    int nwg1 = (Mloc / 128) * 8;
    gemm97<512, true><<<nwg1, 256, 0, stream>>>(
        (const unsigned short*)ub, Bcat, Bu, 8, 2 * NDIM, nullptr, nullptr);

    scan_carry<<<(G * NCHUNK * NDIM) / 256, 256, 0, stream>>>(Bu, lam_re, lam_im, V);
    scan_combine<<<(G * NDIM) / 256, 256, 0, stream>>>(
        V, lamL_re, lamL_im, x0r, x0i, b0, In);
    scan_apply<<<(G * NCHUNK * NDIM) / 256, 256, 0, stream>>>(
        Bu, In, lam_re, lam_im, xsb, fs, b0, fs_mode);

    // GEMM2: outs[M,512] = xsb[M,1024] @ Ccat[512,1024]^T + D*u
    int nwg2 = (Mloc / 128) * 4;
    gemm97<1024, false><<<nwg2, 256, 0, stream>>>(
        (const unsigned short*)xsb, Ccat, outs + (size_t)b0 * TSEQ * HDIM,
        4, HDIM, (const unsigned short*)ub, Dv);
  }
}

// Round 9
// 317.409 us; speedup vs baseline: 1.0968x; 1.0917x over previous
//
#include <hip/hip_runtime.h>

// ---------------- Problem constants ----------------
#define BATCH 16
#define TSEQ  4096
#define HDIM  512
#define NDIM  512
#define NCHUNK 64
#define LCHUNK 64   // TSEQ / NCHUNK

using f32x4  = __attribute__((ext_vector_type(4))) float;
using bf16x8 = __attribute__((ext_vector_type(8))) short;

typedef const __attribute__((address_space(1))) void GV;
typedef __attribute__((address_space(3))) void LV;

__device__ __forceinline__ void gload16(const void* g, void* l) {
  __builtin_amdgcn_global_load_lds((GV*)g, (LV*)l, 16, 0, 0);
}
__device__ __forceinline__ unsigned short f2bf(float f) {
  unsigned u = __float_as_uint(f);
  return (unsigned short)((u + 0x7fffu + ((u >> 16) & 1u)) >> 16);
}
__device__ __forceinline__ float bf2f(unsigned short s) {
  return __uint_as_float(((unsigned)s) << 16);
}

// ---------------- Param prep ----------------
__global__ void prep_params(const float* __restrict__ nu_log,
                            const float* __restrict__ theta_log,
                            float* lam_re, float* lam_im, float* gam,
                            float* lamL_re, float* lamL_im) {
  int n = threadIdx.x;
  float en = expf(nu_log[n]);
  float th = expf(theta_log[n]);
  float r  = expf(-en);
  lam_re[n] = r * cosf(th);
  lam_im[n] = r * sinf(th);
  float r2 = expf(-2.f * en);
  gam[n] = sqrtf(fmaxf(1.f - r2, 0.f));
  float rL  = expf(-(float)LCHUNK * en);
  float thL = (float)LCHUNK * th;
  lamL_re[n] = rL * cosf(thL);
  lamL_im[n] = rL * sinf(thL);
}

__global__ void prep_bcat(const float* __restrict__ B_re, const float* __restrict__ B_im,
                          const float* __restrict__ gam, unsigned short* __restrict__ Bcat) {
  int idx = blockIdx.x * 256 + threadIdx.x;
  int h   = idx & (HDIM - 1);
  int row = idx >> 9;
  int n   = row >> 1;
  float g = gam[n];
  float v = (row & 1) ? B_im[n * HDIM + h] : B_re[n * HDIM + h];
  Bcat[idx] = f2bf(g * v);
}

__global__ void prep_ccat(const float* __restrict__ C_re, const float* __restrict__ C_im,
                          unsigned short* __restrict__ Ccat) {
  int idx = blockIdx.x * 256 + threadIdx.x;
  int col = idx & (2 * NDIM - 1);
  int h   = idx >> 10;
  int n   = col >> 1;
  float v = (col & 1) ? -C_im[h * NDIM + n] : C_re[h * NDIM + n];
  Ccat[idx] = f2bf(v);
}

__global__ void conv_u(const float4* __restrict__ u, ushort4* __restrict__ ub, int n4) {
  int idx = blockIdx.x * 256 + threadIdx.x;
  if (idx >= n4) return;
  float4 v = u[idx];
  ushort4 o;
  o.x = f2bf(v.x); o.y = f2bf(v.y); o.z = f2bf(v.z); o.w = f2bf(v.w);
  ub[idx] = o;
}

// ---------------- 128x128 bf16 MFMA GEMM (m97 structure + T2 swizzle + T1) ----
// C[M,Nd] = A[M,K] @ Bm[Nd,K]^T.  OUTBF: write bf16 (GEMM1->Bu),
// else f32 out + D*u epilogue (GEMM2->outs).
// m97 shape: 256 threads (4 waves, 2x2 of 64x64), BK=64, SINGLE 32KiB LDS
// buffer, plain __syncthreads() pairs.
//  - T2 XOR-swizzle byte ^= ((row&7)<<4), staged via pre-swizzled global src.
//  - T1 XCD chunking, col-block fastest inside each XCD's contiguous chunk.
//  - __launch_bounds__(256, 3): r8 post-mortem -- arch VGPR (112) + acc AGPR
//    (64) = 176/wave -> only 2 blocks/CU (per-tile 1.14us vs m97's 0.61 at 3
//    blocks). Demanding 3 blocks/CU caps the budget at 170/wave, forcing the
//    compiler to trim ~6 regs and restoring m97-parity co-residency.
template <int K, bool OUTBF>
__global__ __launch_bounds__(256, 3)
void gemm97(const unsigned short* __restrict__ A,
            const unsigned short* __restrict__ Bm,
            void* __restrict__ Co, int Ncol, int Nd,
            const unsigned short* __restrict__ ub,
            const float* __restrict__ Dv) {
  __shared__ char lds[32768];  // [A: 0..16383][B: 16384..32767], 128 rows x 128 B each
  const int tid  = threadIdx.x;
  const int wave = tid >> 6, lane = tid & 63;
  const int wr = (wave >> 1) * 64, wc = (wave & 1) * 64;

  // T1: XCD chunking (nwg % 8 == 0), col-block fastest within a chunk.
  int nwg = gridDim.x;
  int bid = blockIdx.x;
  int wg  = (bid & 7) * (nwg >> 3) + (bid >> 3);
  int bn = wg % Ncol, bm = wg / Ncol;
  const long rowBase = (long)bm * 128;
  const long colBase = (long)bn * 128;

  // Pre-swizzled global sources. Linear LDS byte X holds global
  // (row = X>>7, colbyte = (X&127) ^ ((row&7)<<4)).  Per-thread dst
  // X = r*4096 + tid*16 -> row = r*32 + (tid>>3), colE = 8*((tid&7)^((tid>>3)&7))
  const int colE = 8 * ((tid & 7) ^ ((tid >> 3) & 7));
  const unsigned short* srcA[4];
  const unsigned short* srcB[4];
#pragma unroll
  for (int r = 0; r < 4; r++) {
    srcA[r] = A  + (rowBase + r * 32 + (tid >> 3)) * (long)K + colE;
    srcB[r] = Bm + (colBase + r * 32 + (tid >> 3)) * (long)K + colE;
  }

  f32x4 acc[4][4];
#pragma unroll
  for (int i = 0; i < 4; i++)
#pragma unroll
    for (int j = 0; j < 4; j++) acc[i][j] = (f32x4){0.f, 0.f, 0.f, 0.f};

  const int rsub = lane & 15;
  const int sx   = (lane & 7) << 4;      // row&7 == lane&7 for all fragment rows
  const int ke   = (lane >> 4) << 4;     // k-subgroup byte offset (8 elems)

  for (int kt = 0; kt < K; kt += 64) {
    __syncthreads();  // previous tile's readers done before overwrite
#pragma unroll
    for (int r = 0; r < 4; r++) {
      gload16(srcA[r] + kt, &lds[r * 4096 + tid * 16]);
      gload16(srcB[r] + kt, &lds[16384 + r * 4096 + tid * 16]);
    }
    __syncthreads();  // full drain (vmcnt0) + barrier: tile visible to all
#pragma unroll
    for (int kk = 0; kk < 64; kk += 32) {
      bf16x8 af[4], bf[4];
#pragma unroll
      for (int i = 0; i < 4; i++) {
        int off = (((wr + i * 16 + rsub) << 7) + kk * 2 + ke) ^ sx;
        af[i] = *(const bf16x8*)&lds[off];
      }
#pragma unroll
      for (int j = 0; j < 4; j++) {
        int off = 16384 + ((((wc + j * 16 + rsub) << 7) + kk * 2 + ke) ^ sx);
        bf[j] = *(const bf16x8*)&lds[off];
      }
#pragma unroll
      for (int i = 0; i < 4; i++)
#pragma unroll
        for (int j = 0; j < 4; j++)
          acc[i][j] = __builtin_amdgcn_mfma_f32_16x16x32_bf16(af[i], bf[j], acc[i][j], 0, 0, 0);
    }
  }

  // Epilogue (proven mapping: col=lane&15, row=(lane>>4)*4+r)
  const int cc = lane & 15, r4 = (lane >> 4) * 4;
#pragma unroll
  for (int i = 0; i < 4; i++) {
#pragma unroll
    for (int j = 0; j < 4; j++) {
      long col = colBase + wc + j * 16 + cc;
#pragma unroll
      for (int r = 0; r < 4; r++) {
        long row = rowBase + wr + i * 16 + r4 + r;
        if (OUTBF) {
          ((unsigned short*)Co)[row * (long)Nd + col] = f2bf(acc[i][j][r]);
        } else {
          float d = Dv[col];
          ((float*)Co)[row * (long)Nd + col] =
              acc[i][j][r] + d * bf2f(ub[row * (long)Nd + col]);
        }
      }
    }
  }
}

// ---------------- Chunked complex scan (Bu packed bf16 re|im) ----------------
__global__ void scan_carry(const unsigned* __restrict__ Bu,
                           const float* __restrict__ lam_re, const float* __restrict__ lam_im,
                           float2* __restrict__ V) {
  int idx  = blockIdx.x * 256 + threadIdx.x;
  int n    = idx & (NDIM - 1);
  int c    = (idx >> 9) & (NCHUNK - 1);
  int bloc = idx >> 15;
  float lr = lam_re[n], li = lam_im[n];
  float xr = 0.f, xi = 0.f;
  long base = ((long)bloc * TSEQ + c * LCHUNK) * NDIM + n;
#pragma unroll 4
  for (int j = 0; j < LCHUNK; j++) {
    unsigned pv = Bu[base + (long)j * NDIM];
    float br = bf2f((unsigned short)(pv & 0xffff));
    float bi = bf2f((unsigned short)(pv >> 16));
    float nr = lr * xr - li * xi + br;
    float ni = lr * xi + li * xr + bi;
    xr = nr; xi = ni;
  }
  V[idx] = make_float2(xr, xi);
}

__global__ void scan_combine(const float2* __restrict__ V,
                             const float* __restrict__ lamL_re, const float* __restrict__ lamL_im,
                             const float* __restrict__ x0r, const float* __restrict__ x0i,
                             int b0, float2* __restrict__ In) {
  int idx  = blockIdx.x * 256 + threadIdx.x;
  int n    = idx & (NDIM - 1);
  int bloc = idx >> 9;
  int b    = b0 + bloc;
  float lr = lamL_re[n], li = lamL_im[n];
  float sr = x0r[b * NDIM + n], si = x0i[b * NDIM + n];
  long base = (long)bloc * NCHUNK * NDIM + n;
  for (int c = 0; c < NCHUNK; c++) {
    In[base + c * NDIM] = make_float2(sr, si);
    float2 v = V[base + c * NDIM];
    float nr = lr * sr - li * si + v.x;
    float ni = lr * si + li * sr + v.y;
    sr = nr; si = ni;
  }
}

__global__ void scan_apply(const unsigned* __restrict__ Bu, const float2* __restrict__ In,
                           const float* __restrict__ lam_re, const float* __restrict__ lam_im,
                           unsigned int* __restrict__ xsb, float* __restrict__ fs,
                           int b0, int fs_mode) {
  int idx  = blockIdx.x * 256 + threadIdx.x;
  int n    = idx & (NDIM - 1);
  int c    = (idx >> 9) & (NCHUNK - 1);
  int bloc = idx >> 15;
  float lr = lam_re[n], li = lam_im[n];
  float2 s = In[idx];
  float xr = s.x, xi = s.y;
  long base = ((long)bloc * TSEQ + c * LCHUNK) * NDIM + n;
#pragma unroll 4
  for (int j = 0; j < LCHUNK; j++) {
    unsigned pv = Bu[base + (long)j * NDIM];
    float br = bf2f((unsigned short)(pv & 0xffff));
    float bi = bf2f((unsigned short)(pv >> 16));
    float nr = lr * xr - li * xi + br;
    float ni = lr * xi + li * xr + bi;
    xr = nr; xi = ni;
    xsb[base + (long)j * NDIM] = (unsigned)f2bf(xr) | ((unsigned)f2bf(xi) << 16);
  }
  if (c == NCHUNK - 1 && fs_mode >= 0) {
    int b = b0 + bloc;
    if (fs_mode == 1) {
      fs[(size_t)(b * NDIM + n) * 2]     = xr;
      fs[(size_t)(b * NDIM + n) * 2 + 1] = xi;
    } else {
      fs[(size_t)(b * NDIM + n)] = xr;
    }
  }
}

// ---------------- Host launch ----------------
extern "C" void kernel_launch(void* const* d_in, const int* in_sizes, int n_in,
                              void* d_out, int out_size, void* d_ws, size_t ws_size,
                              hipStream_t stream) {
  const float* x0r       = (const float*)d_in[0];
  const float* x0i       = (const float*)d_in[1];
  const float* u         = (const float*)d_in[2];
  const float* nu_log    = (const float*)d_in[3];
  const float* theta_log = (const float*)d_in[4];
  const float* B_re      = (const float*)d_in[5];
  const float* B_im      = (const float*)d_in[6];
  const float* C_re      = (const float*)d_in[7];
  const float* C_im      = (const float*)d_in[8];
  const float* Dv        = (const float*)d_in[9];

  char* ws = (char*)d_ws;
  size_t off = 0;
  auto alloc = [&](size_t bytes) {
    char* p = ws + off;
    off = (off + bytes + 255) & ~(size_t)255;
    return p;
  };

  float* lam_re  = (float*)alloc(NDIM * 4);
  float* lam_im  = (float*)alloc(NDIM * 4);
  float* gam     = (float*)alloc(NDIM * 4);
  float* lamL_re = (float*)alloc(NDIM * 4);
  float* lamL_im = (float*)alloc(NDIM * 4);
  unsigned short* Bcat = (unsigned short*)alloc((size_t)2 * NDIM * HDIM * 2);
  unsigned short* Ccat = (unsigned short*)alloc((size_t)HDIM * 2 * NDIM * 2);

  const size_t per_batch =
      (size_t)TSEQ * HDIM * 2 +       // u bf16
      (size_t)TSEQ * NDIM * 4 +       // Bu packed bf16 (re|im)
      (size_t)TSEQ * NDIM * 4 +       // xs packed bf16
      (size_t)2 * NCHUNK * NDIM * 8 + // V, In
      4096;
  int G = 16;
  while (G > 1 && off + (size_t)G * per_batch > ws_size) G >>= 1;

  ushort4*      ub  = (ushort4*)alloc((size_t)G * TSEQ * HDIM * 2);
  unsigned*     Bu  = (unsigned*)alloc((size_t)G * TSEQ * NDIM * 4);
  unsigned int* xsb = (unsigned int*)alloc((size_t)G * TSEQ * NDIM * 4);
  float2*       V   = (float2*)alloc((size_t)G * NCHUNK * NDIM * 8);
  float2*       In  = (float2*)alloc((size_t)G * NCHUNK * NDIM * 8);

  const long outs_elems = (long)BATCH * TSEQ * HDIM;
  long out0 = (long)out_size - outs_elems;
  int fs_mode;
  if (out0 >= 16384)     fs_mode = 1;
  else if (out0 >= 8192) fs_mode = 0;
  else { out0 = 0;       fs_mode = -1; }

  float* fs   = (float*)d_out;
  float* outs = (float*)d_out + out0;

  prep_params<<<1, NDIM, 0, stream>>>(nu_log, theta_log, lam_re, lam_im, gam, lamL_re, lamL_im);
  prep_bcat<<<(2 * NDIM * HDIM) / 256, 256, 0, stream>>>(B_re, B_im, gam, Bcat);
  prep_ccat<<<(HDIM * 2 * NDIM) / 256, 256, 0, stream>>>(C_re, C_im, Ccat);

  for (int b0 = 0; b0 < BATCH; b0 += G) {
    const float* ug = u + (size_t)b0 * TSEQ * HDIM;
    int Mloc = G * TSEQ;
    int n4 = Mloc * HDIM / 4;
    conv_u<<<(n4 + 255) / 256, 256, 0, stream>>>((const float4*)ug, ub, n4);

    // GEMM1: Bu[M, 2N] (bf16 packed) = ub[M,512] @ Bcat[1024,512]^T
    int nwg1 = (Mloc / 128) * 8;
    gemm97<512, true><<<nwg1, 256, 0, stream>>>(
        (const unsigned short*)ub, Bcat, Bu, 8, 2 * NDIM, nullptr, nullptr);

    scan_carry<<<(G * NCHUNK * NDIM) / 256, 256, 0, stream>>>(Bu, lam_re, lam_im, V);
    scan_combine<<<(G * NDIM) / 256, 256, 0, stream>>>(
        V, lamL_re, lamL_im, x0r, x0i, b0, In);
    scan_apply<<<(G * NCHUNK * NDIM) / 256, 256, 0, stream>>>(
        Bu, In, lam_re, lam_im, xsb, fs, b0, fs_mode);

    // GEMM2: outs[M,512] = xsb[M,1024] @ Ccat[512,1024]^T + D*u
    int nwg2 = (Mloc / 128) * 4;
    gemm97<1024, false><<<nwg2, 256, 0, stream>>>(
        (const unsigned short*)xsb, Ccat, outs + (size_t)b0 * TSEQ * HDIM,
        4, HDIM, (const unsigned short*)ub, Dv);
  }
}